// Round 12
// baseline (852.483 us; speedup 1.0000x reference)
//
#include <hip/hip_runtime.h>
#include <hip/hip_bf16.h>

using bf16 = __hip_bfloat16;
typedef unsigned short ushort_t;
typedef __attribute__((ext_vector_type(8))) short v8s;
typedef __attribute__((ext_vector_type(4))) float v4f;

__device__ __forceinline__ float bfbits2f(unsigned u) {
    return __uint_as_float(u << 16);
}
__device__ __forceinline__ ushort_t f2bfbits(float f) {
    unsigned x = __float_as_uint(f);
    return (ushort_t)((x + 0x7fffu + ((x >> 16) & 1u)) >> 16);
}
// dtype-adaptive input load / output store (flag: 1 = fp32 buffers, 0 = bf16)
__device__ __forceinline__ float ldin(const void* p, size_t i, int f32) {
    return f32 ? ((const float*)p)[i] : bfbits2f(((const ushort_t*)p)[i]);
}
__device__ __forceinline__ void stout(void* p, size_t i, float v, int f32) {
    if (f32) ((float*)p)[i] = v;
    else     ((ushort_t*)p)[i] = f2bfbits(v);
}

// ---------------- sizes ----------------
#define B_   4
#define CC   64
#define HC   64
#define WC   64
#define JC   4096
#define CF   24
#define HF   128
#define WF   128
#define JF   16384
#define OUT0_ELEMS (B_ * 3 * JC)

// =====================================================================
// Kernel 0: dtype probe. flag=1 -> fp32 inputs (R3: confirmed fp32).
// =====================================================================
__global__ void dtype_probe_kernel(const ushort_t* __restrict__ x,
                                   int* __restrict__ flag)
{
    __shared__ int cnt;
    if (threadIdx.x == 0) cnt = 0;
    __syncthreads();
    int c = 0;
    for (int i = threadIdx.x; i < 8192; i += 256) {
        const unsigned e = (x[i] >> 7) & 0xFF;
        if (e >= 0x89) ++c;
    }
    atomicAdd(&cnt, c);
    __syncthreads();
    if (threadIdx.x == 0) *flag = (cnt > 64) ? 1 : 0;
}

// =====================================================================
// Fine weight repack: w[co][ci][3][3] -> wp[k][co][ci_pad] bf16
// =====================================================================
__global__ void repack_w_kernel(const void* __restrict__ w, ushort_t* __restrict__ wp,
                                int CO, int CIreal, int CIP, const int* __restrict__ dflag)
{
    const int f32 = *dflag;
    const int idx = blockIdx.x * 256 + threadIdx.x;
    const int total = 9 * CO * CIP;
    if (idx >= total) return;
    const int k = idx / (CO * CIP);
    const int rem = idx - k * (CO * CIP);
    const int co = rem / CIP;
    const int cip = rem - co * CIP;
    float v = 0.f;
    if (cip < CIreal) v = ldin(w, ((size_t)co * CIreal + cip) * 9 + k, f32);
    wp[((size_t)k * CO + co) * CIP + cip] = f2bfbits(v);
}

// =====================================================================
// Coarse weight repack into MFMA FRAGMENT order, split hi/lo.
// =====================================================================
__global__ void repack_wfrag_kernel(const void* __restrict__ w, ushort_t* __restrict__ wfrag,
                                    int CIreal, int nch, const int* __restrict__ dflag)
{
    const int f32 = *dflag;
    const int idx = blockIdx.x * 256 + threadIdx.x;
    const int total = 8 * 9 * 2 * 2 * nch * 64;
    if (idx >= total) return;
    const int ln = idx & 63;
    int t = idx >> 6;
    const int ch = t % nch; t /= nch;
    const int pl = t & 1; t >>= 1;
    const int nt = t & 1; t >>= 1;
    const int k = t % 9;
    const int cog = t / 9;
    const int co = cog * 32 + nt * 16 + (ln & 15);
    const int cib = ch * 32 + (ln >> 4) * 8;
    ushort_t vals[8];
#pragma unroll
    for (int e = 0; e < 8; ++e) {
        const int ci = cib + e;
        float v = 0.f;
        if (ci < CIreal) v = ldin(w, ((size_t)co * CIreal + ci) * 9 + k, f32);
        const ushort_t h = f2bfbits(v);
        vals[e] = pl ? f2bfbits(v - bfbits2f(h)) : h;
    }
    uint4 o;
    o.x = (unsigned)vals[0] | ((unsigned)vals[1] << 16);
    o.y = (unsigned)vals[2] | ((unsigned)vals[3] << 16);
    o.z = (unsigned)vals[4] | ((unsigned)vals[5] << 16);
    o.w = (unsigned)vals[6] | ((unsigned)vals[7] << 16);
    *(uint4*)&wfrag[(size_t)idx * 8] = o;
}

// =====================================================================
// Kernel 1a: split-transpose feats: [b][64ch][4096px] -> [b][4096px][64ch]
// =====================================================================
__global__ __launch_bounds__(256) void split_transpose_kernel(
    const void* __restrict__ src, ushort_t* __restrict__ hi,
    ushort_t* __restrict__ lo, const int* __restrict__ dflag)
{
    const int f32 = *dflag;
    __shared__ float t[64][65];
    const int blk = blockIdx.x;
    const int b = blk >> 6;
    const int px0 = (blk & 63) * 64;
    const int tid = threadIdx.x;
    const int px = tid & 63;
    for (int i = 0; i < 16; ++i) {
        const int c = (tid >> 6) + 4 * i;
        t[px][c] = ldin(src, ((size_t)b * 64 + c) * 4096 + px0 + px, f32);
    }
    __syncthreads();
    for (int it = 0; it < 2; ++it) {
        const int p = tid + it * 256;
        const int opx = p >> 3, chk = (p & 7) * 8;
        unsigned hh[4], ll[4];
#pragma unroll
        for (int e = 0; e < 4; ++e) {
            const float v0 = t[opx][chk + 2 * e];
            const float v1 = t[opx][chk + 2 * e + 1];
            const ushort_t h0 = f2bfbits(v0);
            const ushort_t h1 = f2bfbits(v1);
            hh[e] = (unsigned)h0 | ((unsigned)h1 << 16);
            ll[e] = (unsigned)f2bfbits(v0 - bfbits2f(h0))
                  | ((unsigned)f2bfbits(v1 - bfbits2f(h1)) << 16);
        }
        const size_t obase = ((size_t)b * 4096 + px0 + opx) * 64 + chk;
        *(uint4*)&hi[obase] = make_uint4(hh[0], hh[1], hh[2], hh[3]);
        *(uint4*)&lo[obase] = make_uint4(ll[0], ll[1], ll[2], ll[3]);
    }
}

// =====================================================================
// Kernel 1b: correlation, SPLIT-K: grid (HC, B, 4). Each block: 64 q x
// 1024 keys (8 chunks of 128). Writes unnormalized partials (l, px, py).
// =====================================================================
#define KCH 128
__global__ __launch_bounds__(256) void corr_mfma_kernel(
    const ushort_t* __restrict__ qhi, const ushort_t* __restrict__ qlo,
    const ushort_t* __restrict__ khi, const ushort_t* __restrict__ klo,
    float* __restrict__ part)
{
    __shared__ ushort_t kbh[KCH * 72];
    __shared__ ushort_t kbl[KCH * 72];
    __shared__ float red[4][64][3];
    const int h = blockIdx.x, b = blockIdx.y, sl = blockIdx.z;
    const int tid = threadIdx.x;
    const int wv = tid >> 6, ln = tid & 63;
    const int lm = ln & 15, quad = ln >> 4, q8 = quad * 8;

    v8s qf[4][2][2];
#pragma unroll
    for (int mt = 0; mt < 4; ++mt)
#pragma unroll
        for (int kc = 0; kc < 2; ++kc) {
            const size_t qoff = ((size_t)b * 4096 + h * 64 + mt * 16 + lm) * 64 + kc * 32 + q8;
            qf[mt][kc][0] = *(const v8s*)&qhi[qoff];
            qf[mt][kc][1] = *(const v8s*)&qlo[qoff];
        }

    float P[4][4][3];
#pragma unroll
    for (int mt = 0; mt < 4; ++mt)
#pragma unroll
        for (int i = 0; i < 4; ++i)
            P[mt][i][0] = P[mt][i][1] = P[mt][i][2] = 0.f;

    const size_t kbase = (size_t)b * 4096 * 64;
    for (int c = 0; c < 1024 / KCH; ++c) {
        const int j0 = sl * 1024 + c * KCH;
        __syncthreads();
        for (int p = tid; p < 2048; p += 256) {
            const int pl = p >> 10;
            const int r = p & 1023;
            const int key = r >> 3, chk = (r & 7) * 8;
            const ushort_t* gsrc = pl ? klo : khi;
            const uint4 v = *(const uint4*)&gsrc[kbase + (size_t)(j0 + key) * 64 + chk];
            ushort_t* dst = pl ? kbl : kbh;
            *(uint4*)&dst[key * 72 + chk] = v;
        }
        __syncthreads();

#pragma unroll
        for (int nt = 0; nt < 2; ++nt) {
            const int kb = wv * 32 + nt * 16;
            const int j = j0 + kb + lm;
            const float gx = (float)((j & 63) * 2 + 1) * (1.f / 64.f) - 1.f;
            const float gy = (float)((j >> 6) * 2 + 1) * (1.f / 64.f) - 1.f;
            const v8s bh0 = *(const v8s*)&kbh[(kb + lm) * 72 + q8];
            const v8s bh1 = *(const v8s*)&kbh[(kb + lm) * 72 + 32 + q8];
            const v8s bl0 = *(const v8s*)&kbl[(kb + lm) * 72 + q8];
            const v8s bl1 = *(const v8s*)&kbl[(kb + lm) * 72 + 32 + q8];
#pragma unroll
            for (int mt = 0; mt < 4; ++mt) {
                v4f acc = (v4f)(0.f);
                acc = __builtin_amdgcn_mfma_f32_16x16x32_bf16(qf[mt][0][0], bl0, acc, 0, 0, 0);
                acc = __builtin_amdgcn_mfma_f32_16x16x32_bf16(qf[mt][0][1], bh0, acc, 0, 0, 0);
                acc = __builtin_amdgcn_mfma_f32_16x16x32_bf16(qf[mt][0][0], bh0, acc, 0, 0, 0);
                acc = __builtin_amdgcn_mfma_f32_16x16x32_bf16(qf[mt][1][0], bl1, acc, 0, 0, 0);
                acc = __builtin_amdgcn_mfma_f32_16x16x32_bf16(qf[mt][1][1], bh1, acc, 0, 0, 0);
                acc = __builtin_amdgcn_mfma_f32_16x16x32_bf16(qf[mt][1][0], bh1, acc, 0, 0, 0);
#pragma unroll
                for (int i = 0; i < 4; ++i) {
                    const float p_ = __expf(acc[i] * 0.125f);
                    P[mt][i][0] += p_;
                    P[mt][i][1] += p_ * gx;
                    P[mt][i][2] += p_ * gy;
                }
            }
        }
    }

#pragma unroll
    for (int mt = 0; mt < 4; ++mt)
#pragma unroll
        for (int i = 0; i < 4; ++i)
#pragma unroll
            for (int d = 0; d < 3; ++d) {
                float v = P[mt][i][d];
                v += __shfl_xor(v, 1);
                v += __shfl_xor(v, 2);
                v += __shfl_xor(v, 4);
                v += __shfl_xor(v, 8);
                P[mt][i][d] = v;
            }
    if (lm == 0) {
#pragma unroll
        for (int mt = 0; mt < 4; ++mt)
#pragma unroll
            for (int i = 0; i < 4; ++i) {
                const int q = mt * 16 + quad * 4 + i;
                red[wv][q][0] = P[mt][i][0];
                red[wv][q][1] = P[mt][i][1];
                red[wv][q][2] = P[mt][i][2];
            }
    }
    __syncthreads();
    if (tid < 64) {
        const int q = tid;
        float l = 0.f, ax = 0.f, ay = 0.f;
        for (int w = 0; w < 4; ++w) {
            l += red[w][q][0]; ax += red[w][q][1]; ay += red[w][q][2];
        }
        const size_t base = (((size_t)sl * B_ + b) * 4096 + h * 64 + q) * 4;
        part[base] = l; part[base + 1] = ax; part[base + 2] = ay;
    }
}

// =====================================================================
// Kernel 1c: merge split-K partials -> cm0 (deterministic)
// =====================================================================
__global__ __launch_bounds__(256) void corr_reduce_kernel(
    const float* __restrict__ part, float* __restrict__ cm0)
{
    const int idx = blockIdx.x * 256 + threadIdx.x;   // B*JC
    const int b = idx >> 12, hq = idx & 4095;
    float l = 0.f, ax = 0.f, ay = 0.f;
    for (int s = 0; s < 4; ++s) {
        const size_t base = (((size_t)s * B_ + b) * 4096 + hq) * 4;
        l += part[base]; ax += part[base + 1]; ay += part[base + 2];
    }
    const float inv = 1.f / l;
    const size_t o = (size_t)b * 3 * JC + hq;
    cm0[o]          = ax * inv;
    cm0[o + JC]     = ay * inv;
    cm0[o + 2 * JC] = 0.f;
}

// =====================================================================
// Kernel 2: coarse concat -> SPLIT hi/lo bf16 NHWC planes [b][px][160]
// =====================================================================
__global__ __launch_bounds__(256) void coarse_concat_split(
    const void* __restrict__ f0c, const void* __restrict__ f1c,
    const float* __restrict__ cm0, ushort_t* __restrict__ hiP,
    ushort_t* __restrict__ loP, const int* __restrict__ dflag)
{
    const int f32 = *dflag;
    const int idx = blockIdx.x * 256 + threadIdx.x;   // B*JC
    const int b = idx >> 12, hw = idx & (JC - 1);
    const size_t ib = (size_t)b * CC * JC;
    ushort_t* oh = hiP + (size_t)idx * 160;
    ushort_t* ol = loP + (size_t)idx * 160;

#pragma unroll 4
    for (int c = 0; c < CC; ++c) {
        const float v = ldin(f0c, ib + (size_t)c * JC + hw, f32);
        const ushort_t h = f2bfbits(v);
        oh[c] = h; ol[c] = f2bfbits(v - bfbits2f(h));
    }

    const float gx = cm0[((size_t)b * 3 + 0) * JC + hw];
    const float gy = cm0[((size_t)b * 3 + 1) * JC + hw];
    const float x = (gx + 1.f) * 32.f - 0.5f;
    const float y = (gy + 1.f) * 32.f - 0.5f;
    const float x0f = floorf(x), y0f = floorf(y);
    const float wx = x - x0f, wy = y - y0f;
    const int x0 = (int)x0f, y0 = (int)y0f;
    const int x1 = x0 + 1, y1 = y0 + 1;
    const float vx0 = (x0 >= 0 && x0 < WC) ? 1.f : 0.f;
    const float vx1 = (x1 >= 0 && x1 < WC) ? 1.f : 0.f;
    const float vy0 = (y0 >= 0 && y0 < HC) ? 1.f : 0.f;
    const float vy1 = (y1 >= 0 && y1 < HC) ? 1.f : 0.f;
    const int cx0 = min(max(x0, 0), WC - 1), cx1 = min(max(x1, 0), WC - 1);
    const int cy0 = min(max(y0, 0), HC - 1), cy1 = min(max(y1, 0), HC - 1);
    const float w00 = (1.f - wx) * (1.f - wy) * vx0 * vy0;
    const float w01 = wx * (1.f - wy) * vx1 * vy0;
    const float w10 = (1.f - wx) * wy * vx0 * vy1;
    const float w11 = wx * wy * vx1 * vy1;
    const int i00 = cy0 * WC + cx0, i01 = cy0 * WC + cx1;
    const int i10 = cy1 * WC + cx0, i11 = cy1 * WC + cx1;

#pragma unroll 4
    for (int c = 0; c < CC; ++c) {
        const size_t pb = ib + (size_t)c * JC;
        const float v = w00 * ldin(f1c, pb + i00, f32) + w01 * ldin(f1c, pb + i01, f32)
                      + w10 * ldin(f1c, pb + i10, f32) + w11 * ldin(f1c, pb + i11, f32);
        const ushort_t h = f2bfbits(v);
        oh[64 + c] = h; ol[64 + c] = f2bfbits(v - bfbits2f(h));
    }
    {
        const ushort_t h = f2bfbits(gx);
        oh[128] = h; ol[128] = f2bfbits(gx - bfbits2f(h));
    }
    {
        const ushort_t h = f2bfbits(gy);
        oh[129] = h; ol[129] = f2bfbits(gy - bfbits2f(h));
    }
    for (int c = 130; c < 160; ++c) { oh[c] = 0; ol[c] = 0; }
}

// =====================================================================
// BN+ReLU+split elementwise: fp32 NHWC 256 -> hi/lo bf16 planes
// =====================================================================
__global__ __launch_bounds__(256) void bnrelu_split_kernel(
    const float* __restrict__ x, const float2* __restrict__ st,
    ushort_t* __restrict__ hiP, ushort_t* __restrict__ loP)
{
    const int idx = blockIdx.x * 256 + threadIdx.x;   // B*JC*32
    const int px = idx >> 5;
    const int c8 = (idx & 31) << 3;
    const float4 v0 = *(const float4*)&x[(size_t)px * 256 + c8];
    const float4 v1 = *(const float4*)&x[(size_t)px * 256 + c8 + 4];
    const float vv[8] = {v0.x, v0.y, v0.z, v0.w, v1.x, v1.y, v1.z, v1.w};
    ushort_t hh[8], ll[8];
#pragma unroll
    for (int e = 0; e < 8; ++e) {
        const float2 s = st[c8 + e];
        const float f = fmaxf((vv[e] - s.x) * s.y, 0.f);
        const ushort_t h = f2bfbits(f);
        hh[e] = h; ll[e] = f2bfbits(f - bfbits2f(h));
    }
    uint4 oh, ol;
    oh.x = (unsigned)hh[0] | ((unsigned)hh[1] << 16);
    oh.y = (unsigned)hh[2] | ((unsigned)hh[3] << 16);
    oh.z = (unsigned)hh[4] | ((unsigned)hh[5] << 16);
    oh.w = (unsigned)hh[6] | ((unsigned)hh[7] << 16);
    ol.x = (unsigned)ll[0] | ((unsigned)ll[1] << 16);
    ol.y = (unsigned)ll[2] | ((unsigned)ll[3] << 16);
    ol.z = (unsigned)ll[4] | ((unsigned)ll[5] << 16);
    ol.w = (unsigned)ll[6] | ((unsigned)ll[7] << 16);
    *(uint4*)&hiP[(size_t)px * 256 + c8] = oh;
    *(uint4*)&loP[(size_t)px * 256 + c8] = ol;
}

// =====================================================================
// Kernel 3a: COARSE 3x3 conv, split-bf16 MFMA + fused BN-stat atomics.
// R12: 8x16 px tile (halo 10x18), grid (32,B,8)=1024 blocks, LDS ~27 KB
// -> 4-6 blocks/CU for staging-latency overlap. mt=2 (acc[2][2]).
// =====================================================================
__global__ __launch_bounds__(256, 4) void conv3x3_wsplit(
    const ushort_t* __restrict__ hiP, const ushort_t* __restrict__ loP,
    const ushort_t* __restrict__ wfrag,
    float* __restrict__ out, float* __restrict__ chsum,
    int CIP, int CO, int H, int W, int tilesX)
{
    __shared__ ushort_t actH[10 * 18 * 36];   // 12960 B
    __shared__ ushort_t actL[10 * 18 * 36];   // 12960 B
    __shared__ float smS[4][2][16], smQ[4][2][16];   // 1 KB

    const int nch = CIP >> 5;
    const int tid = threadIdx.x;
    const int tile = blockIdx.x;
    const int b = blockIdx.y;
    const int cog = blockIdx.z;
    const int ty = (tile / tilesX) * 8;
    const int tx = (tile % tilesX) * 16;
    const int wv = tid >> 6;
    const int ln = tid & 63;
    const int lm = ln & 15;
    const int q8 = (ln >> 4) * 8;

    v4f acc[2][2];
#pragma unroll
    for (int i = 0; i < 2; ++i)
#pragma unroll
        for (int j = 0; j < 2; ++j) acc[i][j] = (v4f)(0.f);

    for (int ch = 0; ch < nch; ++ch) {
        const int ci0 = ch << 5;
        __syncthreads();
        // stage: 2 planes x 10x18 px x 32 ci (1440 uint4)
        for (int p = tid; p < 1440; p += 256) {
            const int pl = (p >= 720) ? 1 : 0;
            const int r = p - pl * 720;
            const int yy = r / 72;
            const int rem = r - yy * 72;
            const int xx = rem >> 2;
            const int cs = (rem & 3) << 3;
            const int gy = ty + yy - 1, gx = tx + xx - 1;
            uint4 val = make_uint4(0u, 0u, 0u, 0u);
            if (gy >= 0 && gy < H && gx >= 0 && gx < W) {
                const ushort_t* src = pl ? loP : hiP;
                val = *(const uint4*)&src[(((size_t)(b * H + gy)) * W + gx) * CIP + ci0 + cs];
            }
            ushort_t* dst = pl ? actL : actH;
            *(uint4*)&dst[(yy * 18 + xx) * 36 + cs] = val;
        }
        __syncthreads();

#pragma unroll
        for (int dx = 0; dx < 3; ++dx) {
            // cache 4 row-fragments (rows wv*2 .. wv*2+3 of the halo tile)
            v8s ah[4], al[4];
#pragma unroll
            for (int rr = 0; rr < 4; ++rr) {
                const int aoff = ((wv * 2 + rr) * 18 + lm + dx) * 36 + q8;
                ah[rr] = *(const v8s*)&actH[aoff];
                al[rr] = *(const v8s*)&actL[aoff];
            }
#pragma unroll
            for (int dy = 0; dy < 3; ++dy) {
                const int k = dy * 3 + dx;
                const size_t fb = (((size_t)(cog * 9 + k) * 4) * nch + ch) * 64 + ln;
                const size_t step = (size_t)nch * 64;
                const v8s bh0 = *(const v8s*)&wfrag[fb * 8];
                const v8s bl0 = *(const v8s*)&wfrag[(fb + step) * 8];
                const v8s bh1 = *(const v8s*)&wfrag[(fb + 2 * step) * 8];
                const v8s bl1 = *(const v8s*)&wfrag[(fb + 3 * step) * 8];
#pragma unroll
                for (int mt = 0; mt < 2; ++mt) {
                    const v8s a_h = ah[mt + dy];
                    const v8s a_l = al[mt + dy];
                    acc[mt][0] = __builtin_amdgcn_mfma_f32_16x16x32_bf16(a_h, bl0, acc[mt][0], 0, 0, 0);
                    acc[mt][0] = __builtin_amdgcn_mfma_f32_16x16x32_bf16(a_l, bh0, acc[mt][0], 0, 0, 0);
                    acc[mt][0] = __builtin_amdgcn_mfma_f32_16x16x32_bf16(a_h, bh0, acc[mt][0], 0, 0, 0);
                    acc[mt][1] = __builtin_amdgcn_mfma_f32_16x16x32_bf16(a_h, bl1, acc[mt][1], 0, 0, 0);
                    acc[mt][1] = __builtin_amdgcn_mfma_f32_16x16x32_bf16(a_l, bh1, acc[mt][1], 0, 0, 0);
                    acc[mt][1] = __builtin_amdgcn_mfma_f32_16x16x32_bf16(a_h, bh1, acc[mt][1], 0, 0, 0);
                }
            }
        }
    }

    // D layout: col(n=co)=ln&15, row(m=x)=(ln>>4)*4+i
#pragma unroll
    for (int mt = 0; mt < 2; ++mt) {
        const int y = ty + wv * 2 + mt;
#pragma unroll
        for (int nt = 0; nt < 2; ++nt) {
            const int co = cog * 32 + nt * 16 + lm;
#pragma unroll
            for (int i = 0; i < 4; ++i) {
                const int x = tx + ((ln >> 4) << 2) + i;
                out[(((size_t)(b * H + y)) * W + x) * CO + co] = acc[mt][nt][i];
            }
        }
    }

    // ---- fused BN-stat partial sums (per-channel sum & sumsq) ----
    float s0 = 0.f, s1 = 0.f, q0 = 0.f, q1 = 0.f;
#pragma unroll
    for (int mt = 0; mt < 2; ++mt)
#pragma unroll
        for (int i = 0; i < 4; ++i) {
            float v = acc[mt][0][i]; s0 += v; q0 += v * v;
            v = acc[mt][1][i]; s1 += v; q1 += v * v;
        }
    s0 += __shfl_xor(s0, 16); s0 += __shfl_xor(s0, 32);
    s1 += __shfl_xor(s1, 16); s1 += __shfl_xor(s1, 32);
    q0 += __shfl_xor(q0, 16); q0 += __shfl_xor(q0, 32);
    q1 += __shfl_xor(q1, 16); q1 += __shfl_xor(q1, 32);
    __syncthreads();
    if (ln < 16) {
        smS[wv][0][ln] = s0; smS[wv][1][ln] = s1;
        smQ[wv][0][ln] = q0; smQ[wv][1][ln] = q1;
    }
    __syncthreads();
    if (tid < 32) {
        const int nt = tid >> 4, l2 = tid & 15;
        float S = 0.f, Q = 0.f;
        for (int w = 0; w < 4; ++w) { S += smS[w][nt][l2]; Q += smQ[w][nt][l2]; }
        const int co = cog * 32 + nt * 16 + l2;
        atomicAdd(&chsum[2 * co], S);
        atomicAdd(&chsum[2 * co + 1], Q);
    }
}

// =====================================================================
// Kernel 3b: FINE 3x3 conv, single-bf16 MFMA + fused BN-stat atomics.
// R12: 8x16 px tile (halo 10x18), grid (128,B,2)=1024 blocks, st[64],
// LDS ~39 KB -> 4 blocks/CU. mt=2 (acc[2][2]).
// =====================================================================
template <bool BN>
__global__ __launch_bounds__(256, 4) void conv3x3_mfma(
    const ushort_t* __restrict__ in,
    const ushort_t* __restrict__ wp,   // [9][CO][CI] bf16
    const float2* __restrict__ stats,
    ushort_t* __restrict__ out, float* __restrict__ chsum,
    int CI, int CO, int H, int W, int tilesX)
{
    __shared__ ushort_t act[10 * 18 * 40];    // 14400 B
    __shared__ ushort_t wbuf[9 * 32 * 40];    // 23040 B
    __shared__ float2 st[64];                 // 512 B (CI=64 only)
    __shared__ float smS[4][2][16], smQ[4][2][16];

    const int tid = threadIdx.x;
    const int tile = blockIdx.x;
    const int b = blockIdx.y;
    const int cog = blockIdx.z;
    const int ty = (tile / tilesX) * 8;
    const int tx = (tile % tilesX) * 16;
    const int wv = tid >> 6;
    const int ln = tid & 63;
    const int lm = ln & 15;
    const int q8 = (ln >> 4) * 8;

    if (BN && tid < 64) st[tid] = stats[tid];

    v4f acc[2][2];
#pragma unroll
    for (int i = 0; i < 2; ++i)
#pragma unroll
        for (int j = 0; j < 2; ++j) acc[i][j] = (v4f)(0.f);

    const int nChunks = CI >> 5;
    for (int ch = 0; ch < nChunks; ++ch) {
        const int ci0 = ch << 5;
        __syncthreads();
        // act: 10x18 px x 32 ci = 720 uint4
        for (int p = tid; p < 720; p += 256) {
            const int yy = p / 72;
            const int rem = p - yy * 72;
            const int xx = rem >> 2;
            const int cs = (rem & 3) << 3;
            const int gy = ty + yy - 1, gx = tx + xx - 1;
            uint4 val = make_uint4(0u, 0u, 0u, 0u);
            if (gy >= 0 && gy < H && gx >= 0 && gx < W) {
                const ushort_t* gp = in + (((size_t)(b * H + gy)) * W + gx) * CI + ci0 + cs;
                val = *(const uint4*)gp;
                if (BN) {
                    unsigned u[4] = {val.x, val.y, val.z, val.w};
                    unsigned o[4];
#pragma unroll
                    for (int e = 0; e < 4; ++e) {
                        float lo = bfbits2f(u[e] & 0xffffu);
                        float hi = bfbits2f(u[e] >> 16);
                        const float2 s0 = st[ci0 + cs + 2 * e];
                        const float2 s1 = st[ci0 + cs + 2 * e + 1];
                        lo = fmaxf((lo - s0.x) * s0.y, 0.f);
                        hi = fmaxf((hi - s1.x) * s1.y, 0.f);
                        o[e] = (unsigned)f2bfbits(lo) | ((unsigned)f2bfbits(hi) << 16);
                    }
                    val = make_uint4(o[0], o[1], o[2], o[3]);
                }
            }
            *(uint4*)&act[(yy * 18 + xx) * 40 + cs] = val;
        }
        for (int p = tid; p < 1152; p += 256) {
            const int k = p / 128;
            const int rem = p - k * 128;
            const int co = rem >> 2;
            const int cs = (rem & 3) << 3;
            const ushort_t* gp = wp + ((size_t)k * CO + cog * 32 + co) * CI + ci0 + cs;
            *(uint4*)&wbuf[(k * 32 + co) * 40 + cs] = *(const uint4*)gp;
        }
        __syncthreads();

#pragma unroll
        for (int dx = 0; dx < 3; ++dx) {
            v8s af[4];
#pragma unroll
            for (int rr = 0; rr < 4; ++rr)
                af[rr] = *(const v8s*)&act[((wv * 2 + rr) * 18 + lm + dx) * 40 + q8];
#pragma unroll
            for (int dy = 0; dy < 3; ++dy) {
                const int k = dy * 3 + dx;
                const v8s bf0 = *(const v8s*)&wbuf[(k * 32 + lm) * 40 + q8];
                const v8s bf1 = *(const v8s*)&wbuf[(k * 32 + 16 + lm) * 40 + q8];
#pragma unroll
                for (int mt = 0; mt < 2; ++mt) {
                    acc[mt][0] = __builtin_amdgcn_mfma_f32_16x16x32_bf16(af[mt + dy], bf0, acc[mt][0], 0, 0, 0);
                    acc[mt][1] = __builtin_amdgcn_mfma_f32_16x16x32_bf16(af[mt + dy], bf1, acc[mt][1], 0, 0, 0);
                }
            }
        }
    }

#pragma unroll
    for (int mt = 0; mt < 2; ++mt) {
        const int y = ty + wv * 2 + mt;
#pragma unroll
        for (int nt = 0; nt < 2; ++nt) {
            const int co = cog * 32 + nt * 16 + lm;
#pragma unroll
            for (int i = 0; i < 4; ++i) {
                const int x = tx + ((ln >> 4) << 2) + i;
                out[(((size_t)(b * H + y)) * W + x) * CO + co] = f2bfbits(acc[mt][nt][i]);
            }
        }
    }

    // ---- fused BN-stat partial sums ----
    float s0 = 0.f, s1 = 0.f, q0 = 0.f, q1 = 0.f;
#pragma unroll
    for (int mt = 0; mt < 2; ++mt)
#pragma unroll
        for (int i = 0; i < 4; ++i) {
            float v = acc[mt][0][i]; s0 += v; q0 += v * v;
            v = acc[mt][1][i]; s1 += v; q1 += v * v;
        }
    s0 += __shfl_xor(s0, 16); s0 += __shfl_xor(s0, 32);
    s1 += __shfl_xor(s1, 16); s1 += __shfl_xor(s1, 32);
    q0 += __shfl_xor(q0, 16); q0 += __shfl_xor(q0, 32);
    q1 += __shfl_xor(q1, 16); q1 += __shfl_xor(q1, 32);
    __syncthreads();
    if (ln < 16) {
        smS[wv][0][ln] = s0; smS[wv][1][ln] = s1;
        smQ[wv][0][ln] = q0; smQ[wv][1][ln] = q1;
    }
    __syncthreads();
    if (tid < 32) {
        const int nt = tid >> 4, l2 = tid & 15;
        float S = 0.f, Q = 0.f;
        for (int w = 0; w < 4; ++w) { S += smS[w][nt][l2]; Q += smQ[w][nt][l2]; }
        const int co = cog * 32 + nt * 16 + l2;
        atomicAdd(&chsum[2 * co], S);
        atomicAdd(&chsum[2 * co + 1], Q);
    }
}

// =====================================================================
// stats finalize: (sum, sumsq) -> (mean, rsqrt(var+eps))
// =====================================================================
__global__ void stats_finalize_kernel(const float* __restrict__ chsum,
                                      float2* __restrict__ st, int C, float inv_n)
{
    const int c = threadIdx.x;
    if (c >= C) return;
    const float mean = chsum[2 * c] * inv_n;
    const float var = chsum[2 * c + 1] * inv_n - mean * mean;
    st[c] = make_float2(mean, 1.0f / sqrtf(var + 1e-5f));
}

// =====================================================================
// Kernel 5: coarse head (fp32 NHWC): 1x1 conv 256->3 + bias + cm0
// =====================================================================
__global__ __launch_bounds__(256) void coarse_head_kernel(
    const float* __restrict__ A, const float2* __restrict__ stats,
    const void* __restrict__ w5, const void* __restrict__ b5,
    float* __restrict__ cm0, void* __restrict__ out,
    const int* __restrict__ dflag)
{
    const int f32 = *dflag;
    __shared__ float wl[3][256];
    __shared__ float bl[3];
    __shared__ float2 st[256];
    const int tid = threadIdx.x;
    for (int i = tid; i < 768; i += 256) wl[i >> 8][i & 255] = ldin(w5, i, f32);
    if (tid < 3) bl[tid] = ldin(b5, tid, f32);
    st[tid] = stats[tid];
    __syncthreads();

    const int idx = blockIdx.x * 256 + tid;
    const int b = idx >> 12, hw = idx & (JC - 1);
    float a0 = bl[0], a1 = bl[1], a2 = bl[2];
    const float* p = A + (size_t)idx * 256;
    for (int c = 0; c < 256; c += 4) {
        const float4 raw = *(const float4*)(p + c);
        const float rv[4] = {raw.x, raw.y, raw.z, raw.w};
#pragma unroll
        for (int e = 0; e < 4; ++e) {
            const int cc = c + e;
            const float v = fmaxf((rv[e] - st[cc].x) * st[cc].y, 0.f);
            a0 += v * wl[0][cc]; a1 += v * wl[1][cc]; a2 += v * wl[2][cc];
        }
    }
    const size_t base = (size_t)b * 3 * JC + hw;
    const float c0 = cm0[base] + a0;
    const float c1 = cm0[base + JC] + a1;
    const float c2 = cm0[base + 2 * JC] + a2;
    cm0[base] = c0; cm0[base + JC] = c1; cm0[base + 2 * JC] = c2;
    stout(out, base, c0, f32);
    stout(out, base + JC, c1, f32);
    stout(out, base + 2 * JC, c2, f32);
}

// =====================================================================
// Kernel 6: bilinear 2x upsample (half-pixel, edge clamp)
// =====================================================================
__global__ __launch_bounds__(256) void upsample_kernel(
    const float* __restrict__ cm, float* __restrict__ up)
{
    const int idx = blockIdx.x * 256 + threadIdx.x;
    const int ox = idx & 127, oy = (idx >> 7) & 127, bc = idx >> 14;
    const float sx = ox * 0.5f - 0.25f;
    const float sy = oy * 0.5f - 0.25f;
    const int x0 = (int)floorf(sx), y0 = (int)floorf(sy);
    const float fx = sx - x0, fy = sy - y0;
    const int cx0 = max(x0, 0), cx1 = min(x0 + 1, WC - 1);
    const int cy0 = max(y0, 0), cy1 = min(y0 + 1, HC - 1);
    const float* p = cm + (size_t)bc * JC;
    const float v = (1.f - fy) * ((1.f - fx) * p[cy0 * WC + cx0] + fx * p[cy0 * WC + cx1])
                  + fy * ((1.f - fx) * p[cy1 * WC + cx0] + fx * p[cy1 * WC + cx1]);
    up[idx] = v;
}

// =====================================================================
// Kernel 7: fine concat -> NHWC bf16 [b][y][x][64] (50 real + 14 zero)
// =====================================================================
__global__ __launch_bounds__(256) void fine_concat_nhwc(
    const void* __restrict__ f0f, const void* __restrict__ f1f,
    const float* __restrict__ up, ushort_t* __restrict__ A,
    const int* __restrict__ dflag)
{
    const int f32 = *dflag;
    const int idx = blockIdx.x * 256 + threadIdx.x;   // B*JF
    const int b = idx >> 14, hw = idx & (JF - 1);
    const size_t ib = (size_t)b * CF * JF;
    ushort_t* o = A + (size_t)idx * 64;

    for (int c = 0; c < CF; ++c)
        o[c] = f2bfbits(ldin(f0f, ib + (size_t)c * JF + hw, f32));

    const size_t ub = (size_t)b * 3 * JF + hw;
    const float gx = up[ub], gy = up[ub + JF];
    const float x = (gx + 1.f) * 64.f - 0.5f;
    const float y = (gy + 1.f) * 64.f - 0.5f;
    const float x0f = floorf(x), y0f = floorf(y);
    const float wx = x - x0f, wy = y - y0f;
    const int x0 = (int)x0f, y0 = (int)y0f;
    const int x1 = x0 + 1, y1 = y0 + 1;
    const float vx0 = (x0 >= 0 && x0 < WF) ? 1.f : 0.f;
    const float vx1 = (x1 >= 0 && x1 < WF) ? 1.f : 0.f;
    const float vy0 = (y0 >= 0 && y0 < HF) ? 1.f : 0.f;
    const float vy1 = (y1 >= 0 && y1 < HF) ? 1.f : 0.f;
    const int cx0 = min(max(x0, 0), WF - 1), cx1 = min(max(x1, 0), WF - 1);
    const int cy0 = min(max(y0, 0), HF - 1), cy1 = min(max(y1, 0), HF - 1);
    const float w00 = (1.f - wx) * (1.f - wy) * vx0 * vy0;
    const float w01 = wx * (1.f - wy) * vx1 * vy0;
    const float w10 = (1.f - wx) * wy * vx0 * vy1;
    const float w11 = wx * wy * vx1 * vy1;
    const int i00 = cy0 * WF + cx0, i01 = cy0 * WF + cx1;
    const int i10 = cy1 * WF + cx0, i11 = cy1 * WF + cx1;

    for (int c = 0; c < CF; ++c) {
        const size_t pb = ib + (size_t)c * JF;
        const float v = w00 * ldin(f1f, pb + i00, f32) + w01 * ldin(f1f, pb + i01, f32)
                      + w10 * ldin(f1f, pb + i10, f32) + w11 * ldin(f1f, pb + i11, f32);
        o[24 + c] = f2bfbits(v);
    }
    o[48] = f2bfbits(gx);
    o[49] = f2bfbits(gy);
    for (int c = 50; c < 64; ++c) o[c] = 0;
}

// =====================================================================
// Kernel 8: fine head (NHWC bf16): 1x1 conv 64->3 + bias + up -> out1
// =====================================================================
__global__ __launch_bounds__(256) void fine_head_kernel(
    const ushort_t* __restrict__ A, const float2* __restrict__ stats,
    const void* __restrict__ w5, const void* __restrict__ b5,
    const float* __restrict__ up, void* __restrict__ out,
    const int* __restrict__ dflag)
{
    const int f32 = *dflag;
    __shared__ float wl[3][64];
    __shared__ float bl[3];
    __shared__ float2 st[64];
    const int tid = threadIdx.x;
    if (tid < 192) wl[tid >> 6][tid & 63] = ldin(w5, tid, f32);
    if (tid < 3) bl[tid] = ldin(b5, tid, f32);
    if (tid < 64) st[tid] = stats[tid];
    __syncthreads();

    const int idx = blockIdx.x * 256 + tid;
    const int b = idx >> 14, hw = idx & (JF - 1);
    float a0 = bl[0], a1 = bl[1], a2 = bl[2];
    const ushort_t* p = A + (size_t)idx * 64;
    for (int c = 0; c < 64; c += 8) {
        const uint4 raw = *(const uint4*)(p + c);
        const unsigned u[4] = {raw.x, raw.y, raw.z, raw.w};
#pragma unroll
        for (int e = 0; e < 4; ++e) {
            const int c0 = c + 2 * e, c1 = c0 + 1;
            float lo = bfbits2f(u[e] & 0xffffu);
            float hi = bfbits2f(u[e] >> 16);
            lo = fmaxf((lo - st[c0].x) * st[c0].y, 0.f);
            hi = fmaxf((hi - st[c1].x) * st[c1].y, 0.f);
            a0 += lo * wl[0][c0] + hi * wl[0][c1];
            a1 += lo * wl[1][c0] + hi * wl[1][c1];
            a2 += lo * wl[2][c0] + hi * wl[2][c1];
        }
    }
    const size_t base = (size_t)b * 3 * JF + hw;
    stout(out, OUT0_ELEMS + base,          up[base] + a0, f32);
    stout(out, OUT0_ELEMS + base + JF,     up[base + JF] + a1, f32);
    stout(out, OUT0_ELEMS + base + 2 * JF, up[base + 2 * JF] + a2, f32);
}

// =====================================================================
extern "C" void kernel_launch(void* const* d_in, const int* in_sizes, int n_in,
                              void* d_out, int out_size, void* d_ws, size_t ws_size,
                              hipStream_t stream)
{
    const void* f0c = d_in[0];
    const void* f1c = d_in[1];
    const void* f0f = d_in[2];
    const void* f1f = d_in[3];
    const void* cw1 = d_in[4];
    const void* cw2 = d_in[5];
    const void* cw3 = d_in[6];
    const void* cw4 = d_in[7];
    const void* cw5 = d_in[8];
    const void* cb5 = d_in[9];
    const void* fw1 = d_in[10];
    const void* fw2 = d_in[11];
    const void* fw3 = d_in[12];
    const void* fw4 = d_in[13];
    const void* fw5 = d_in[14];
    const void* fb5 = d_in[15];

    // ---- workspace layout (same proven footprint) ----
    char* wsb = (char*)d_ws;
    float* bufA    = (float*)wsb;                       // 16 MiB
    float* bufB    = (float*)(wsb + 16777216);          // 16 MiB
    float* cm0     = (float*)(wsb + 33554432);          // 196,608 B
    float* up      = (float*)(wsb + 33751040);          // 786,432 B
    float* chsum   = (float*)(wsb + 34537472);          // 2,048 B
    float2* st_g   = (float2*)(wsb + 34668544);         // 2,048 B
    int* dflag     = (int*)(wsb + 34670592);            // 64 B
    ushort_t* fwp  = (ushort_t*)(wsb + 34670656);       // 294,912 B
    ushort_t* fw1p = fwp;
    ushort_t* fw2p = fwp + 36864;
    ushort_t* fw3p = fwp + 73728;
    ushort_t* fw4p = fwp + 110592;
    ushort_t* wfrag = (ushort_t*)(wsb + 34965568);      // up to 9,437,184 B

    // split activation planes: hi = bufA[0..8MB), lo = bufA[8..16MB)
    ushort_t* hiP = (ushort_t*)bufA;
    ushort_t* loP = (ushort_t*)(wsb + 8388608);

    // corr split Q/K planes in bufA's first 8 MB (dead before concat)
    ushort_t* qhi = (ushort_t*)bufA;
    ushort_t* qlo = qhi + 1048576;
    ushort_t* khi = qlo + 1048576;
    ushort_t* klo = khi + 1048576;
    float* cpart = (float*)bufB;   // 1 MB corr partials (bufB dead during corr)

    ushort_t* fF1 = (ushort_t*)bufB;   // fine ping
    ushort_t* fF2 = (ushort_t*)bufA;   // fine pong

    // 0. dtype probe
    dtype_probe_kernel<<<1, 256, 0, stream>>>((const ushort_t*)f0c, dflag);

    // fine weight repacks (bf16 [k][co][ci_pad])
    repack_w_kernel<<<(9 * 64 * 64 + 255) / 256, 256, 0, stream>>>(fw1, fw1p, 64, 50, 64, dflag);
    repack_w_kernel<<<(9 * 64 * 64 + 255) / 256, 256, 0, stream>>>(fw2, fw2p, 64, 64, 64, dflag);
    repack_w_kernel<<<(9 * 64 * 64 + 255) / 256, 256, 0, stream>>>(fw3, fw3p, 64, 64, 64, dflag);
    repack_w_kernel<<<(9 * 64 * 64 + 255) / 256, 256, 0, stream>>>(fw4, fw4p, 64, 64, 64, dflag);

    // 1. correlation: split-transpose Q/K, split-K MFMA, reduce
    split_transpose_kernel<<<dim3(B_ * 64), 256, 0, stream>>>(f0c, qhi, qlo, dflag);
    split_transpose_kernel<<<dim3(B_ * 64), 256, 0, stream>>>(f1c, khi, klo, dflag);
    corr_mfma_kernel<<<dim3(HC, B_, 4), 256, 0, stream>>>(qhi, qlo, khi, klo, cpart);
    corr_reduce_kernel<<<dim3(B_ * JC / 256), 256, 0, stream>>>(cpart, cm0);

    // 2. coarse concat -> split planes (CIP=160); overwrites q/k (dead)
    coarse_concat_split<<<dim3(B_ * JC / 256), 256, 0, stream>>>(f0c, f1c, cm0, hiP, loP, dflag);

    // 3. coarse conv stack: 8x16 tiles, 1024 blocks, fused stats
    const dim3 cgrid(32, B_, 8);
    repack_wfrag_kernel<<<(8 * 9 * 2 * 2 * 5 * 64 + 255) / 256, 256, 0, stream>>>(cw1, wfrag, 130, 5, dflag);
    hipMemsetAsync(chsum, 0, 2048, stream);
    conv3x3_wsplit<<<cgrid, 256, 0, stream>>>(hiP, loP, wfrag, bufB, chsum, 160, 256, HC, WC, 4);
    stats_finalize_kernel<<<1, 256, 0, stream>>>(chsum, st_g, 256, 1.f / 16384.f);

    bnrelu_split_kernel<<<B_ * JC * 32 / 256, 256, 0, stream>>>(bufB, st_g, hiP, loP);
    repack_wfrag_kernel<<<(8 * 9 * 2 * 2 * 8 * 64 + 255) / 256, 256, 0, stream>>>(cw2, wfrag, 256, 8, dflag);
    hipMemsetAsync(chsum, 0, 2048, stream);
    conv3x3_wsplit<<<cgrid, 256, 0, stream>>>(hiP, loP, wfrag, bufB, chsum, 256, 256, HC, WC, 4);
    stats_finalize_kernel<<<1, 256, 0, stream>>>(chsum, st_g, 256, 1.f / 16384.f);

    bnrelu_split_kernel<<<B_ * JC * 32 / 256, 256, 0, stream>>>(bufB, st_g, hiP, loP);
    repack_wfrag_kernel<<<(8 * 9 * 2 * 2 * 8 * 64 + 255) / 256, 256, 0, stream>>>(cw3, wfrag, 256, 8, dflag);
    hipMemsetAsync(chsum, 0, 2048, stream);
    conv3x3_wsplit<<<cgrid, 256, 0, stream>>>(hiP, loP, wfrag, bufB, chsum, 256, 256, HC, WC, 4);
    stats_finalize_kernel<<<1, 256, 0, stream>>>(chsum, st_g, 256, 1.f / 16384.f);

    bnrelu_split_kernel<<<B_ * JC * 32 / 256, 256, 0, stream>>>(bufB, st_g, hiP, loP);
    repack_wfrag_kernel<<<(8 * 9 * 2 * 2 * 8 * 64 + 255) / 256, 256, 0, stream>>>(cw4, wfrag, 256, 8, dflag);
    hipMemsetAsync(chsum, 0, 2048, stream);
    conv3x3_wsplit<<<cgrid, 256, 0, stream>>>(hiP, loP, wfrag, bufB, chsum, 256, 256, HC, WC, 4);
    stats_finalize_kernel<<<1, 256, 0, stream>>>(chsum, st_g, 256, 1.f / 16384.f);

    // 4. coarse head -> out0, cmatch (in place over cm0)
    coarse_head_kernel<<<dim3(B_ * JC / 256), 256, 0, stream>>>(bufB, st_g, cw5, cb5, cm0, d_out, dflag);

    // 5. upsample (cm0 now holds cmatch)
    upsample_kernel<<<dim3(B_ * 3 * JF / 256), 256, 0, stream>>>(cm0, up);

    // 6. fine concat -> fF1 (bufB region; conv4 raw dead after head)
    fine_concat_nhwc<<<dim3(B_ * JF / 256), 256, 0, stream>>>(f0f, f1f, up, fF1, dflag);

    // 7. fine conv stack: 8x16 tiles, 1024 blocks, fused stats
    const dim3 fgrid(128, B_, 2);
    hipMemsetAsync(chsum, 0, 512, stream);
    conv3x3_mfma<false><<<fgrid, 256, 0, stream>>>(fF1, fw1p, nullptr, fF2, chsum, 64, 64, HF, WF, 8);
    stats_finalize_kernel<<<1, 256, 0, stream>>>(chsum, st_g, 64, 1.f / 65536.f);
    hipMemsetAsync(chsum, 0, 512, stream);
    conv3x3_mfma<true><<<fgrid, 256, 0, stream>>>(fF2, fw2p, st_g, fF1, chsum, 64, 64, HF, WF, 8);
    stats_finalize_kernel<<<1, 256, 0, stream>>>(chsum, st_g, 64, 1.f / 65536.f);
    hipMemsetAsync(chsum, 0, 512, stream);
    conv3x3_mfma<true><<<fgrid, 256, 0, stream>>>(fF1, fw3p, st_g, fF2, chsum, 64, 64, HF, WF, 8);
    stats_finalize_kernel<<<1, 256, 0, stream>>>(chsum, st_g, 64, 1.f / 65536.f);
    hipMemsetAsync(chsum, 0, 512, stream);
    conv3x3_mfma<true><<<fgrid, 256, 0, stream>>>(fF2, fw4p, st_g, fF1, chsum, 64, 64, HF, WF, 8);
    stats_finalize_kernel<<<1, 256, 0, stream>>>(chsum, st_g, 64, 1.f / 65536.f);

    // 8. fine head -> out1
    fine_head_kernel<<<dim3(B_ * JF / 256), 256, 0, stream>>>(fF1, st_g, fw5, fb5, up, d_out, dflag);
}

// Round 13
// 798.429 us; speedup vs baseline: 1.0677x; 1.0677x over previous
//
#include <hip/hip_runtime.h>
#include <hip/hip_bf16.h>

using bf16 = __hip_bfloat16;
typedef unsigned short ushort_t;
typedef __attribute__((ext_vector_type(8))) short v8s;
typedef __attribute__((ext_vector_type(4))) float v4f;

__device__ __forceinline__ float bfbits2f(unsigned u) {
    return __uint_as_float(u << 16);
}
__device__ __forceinline__ ushort_t f2bfbits(float f) {
    unsigned x = __float_as_uint(f);
    return (ushort_t)((x + 0x7fffu + ((x >> 16) & 1u)) >> 16);
}
// dtype-adaptive input load / output store (flag: 1 = fp32 buffers, 0 = bf16)
__device__ __forceinline__ float ldin(const void* p, size_t i, int f32) {
    return f32 ? ((const float*)p)[i] : bfbits2f(((const ushort_t*)p)[i]);
}
__device__ __forceinline__ void stout(void* p, size_t i, float v, int f32) {
    if (f32) ((float*)p)[i] = v;
    else     ((ushort_t*)p)[i] = f2bfbits(v);
}

// ---------------- sizes ----------------
#define B_   4
#define CC   64
#define HC   64
#define WC   64
#define JC   4096
#define CF   24
#define HF   128
#define WF   128
#define JF   16384
#define OUT0_ELEMS (B_ * 3 * JC)

// =====================================================================
// Kernel 0: dtype probe. flag=1 -> fp32 inputs (R3: confirmed fp32).
// =====================================================================
__global__ void dtype_probe_kernel(const ushort_t* __restrict__ x,
                                   int* __restrict__ flag)
{
    __shared__ int cnt;
    if (threadIdx.x == 0) cnt = 0;
    __syncthreads();
    int c = 0;
    for (int i = threadIdx.x; i < 8192; i += 256) {
        const unsigned e = (x[i] >> 7) & 0xFF;
        if (e >= 0x89) ++c;
    }
    atomicAdd(&cnt, c);
    __syncthreads();
    if (threadIdx.x == 0) *flag = (cnt > 64) ? 1 : 0;
}

// =====================================================================
// Fine weight repack: w[co][ci][3][3] -> wp[k][co][ci_pad] bf16
// =====================================================================
__global__ void repack_w_kernel(const void* __restrict__ w, ushort_t* __restrict__ wp,
                                int CO, int CIreal, int CIP, const int* __restrict__ dflag)
{
    const int f32 = *dflag;
    const int idx = blockIdx.x * 256 + threadIdx.x;
    const int total = 9 * CO * CIP;
    if (idx >= total) return;
    const int k = idx / (CO * CIP);
    const int rem = idx - k * (CO * CIP);
    const int co = rem / CIP;
    const int cip = rem - co * CIP;
    float v = 0.f;
    if (cip < CIreal) v = ldin(w, ((size_t)co * CIreal + cip) * 9 + k, f32);
    wp[((size_t)k * CO + co) * CIP + cip] = f2bfbits(v);
}

// =====================================================================
// Coarse weight repack into MFMA FRAGMENT order, split hi/lo.
// =====================================================================
__global__ void repack_wfrag_kernel(const void* __restrict__ w, ushort_t* __restrict__ wfrag,
                                    int CIreal, int nch, const int* __restrict__ dflag)
{
    const int f32 = *dflag;
    const int idx = blockIdx.x * 256 + threadIdx.x;
    const int total = 8 * 9 * 2 * 2 * nch * 64;
    if (idx >= total) return;
    const int ln = idx & 63;
    int t = idx >> 6;
    const int ch = t % nch; t /= nch;
    const int pl = t & 1; t >>= 1;
    const int nt = t & 1; t >>= 1;
    const int k = t % 9;
    const int cog = t / 9;
    const int co = cog * 32 + nt * 16 + (ln & 15);
    const int cib = ch * 32 + (ln >> 4) * 8;
    ushort_t vals[8];
#pragma unroll
    for (int e = 0; e < 8; ++e) {
        const int ci = cib + e;
        float v = 0.f;
        if (ci < CIreal) v = ldin(w, ((size_t)co * CIreal + ci) * 9 + k, f32);
        const ushort_t h = f2bfbits(v);
        vals[e] = pl ? f2bfbits(v - bfbits2f(h)) : h;
    }
    uint4 o;
    o.x = (unsigned)vals[0] | ((unsigned)vals[1] << 16);
    o.y = (unsigned)vals[2] | ((unsigned)vals[3] << 16);
    o.z = (unsigned)vals[4] | ((unsigned)vals[5] << 16);
    o.w = (unsigned)vals[6] | ((unsigned)vals[7] << 16);
    *(uint4*)&wfrag[(size_t)idx * 8] = o;
}

// =====================================================================
// Kernel 1a: split-transpose feats: [b][64ch][4096px] -> [b][4096px][64ch]
// =====================================================================
__global__ __launch_bounds__(256) void split_transpose_kernel(
    const void* __restrict__ src, ushort_t* __restrict__ hi,
    ushort_t* __restrict__ lo, const int* __restrict__ dflag)
{
    const int f32 = *dflag;
    __shared__ float t[64][65];
    const int blk = blockIdx.x;
    const int b = blk >> 6;
    const int px0 = (blk & 63) * 64;
    const int tid = threadIdx.x;
    const int px = tid & 63;
    for (int i = 0; i < 16; ++i) {
        const int c = (tid >> 6) + 4 * i;
        t[px][c] = ldin(src, ((size_t)b * 64 + c) * 4096 + px0 + px, f32);
    }
    __syncthreads();
    for (int it = 0; it < 2; ++it) {
        const int p = tid + it * 256;
        const int opx = p >> 3, chk = (p & 7) * 8;
        unsigned hh[4], ll[4];
#pragma unroll
        for (int e = 0; e < 4; ++e) {
            const float v0 = t[opx][chk + 2 * e];
            const float v1 = t[opx][chk + 2 * e + 1];
            const ushort_t h0 = f2bfbits(v0);
            const ushort_t h1 = f2bfbits(v1);
            hh[e] = (unsigned)h0 | ((unsigned)h1 << 16);
            ll[e] = (unsigned)f2bfbits(v0 - bfbits2f(h0))
                  | ((unsigned)f2bfbits(v1 - bfbits2f(h1)) << 16);
        }
        const size_t obase = ((size_t)b * 4096 + px0 + opx) * 64 + chk;
        *(uint4*)&hi[obase] = make_uint4(hh[0], hh[1], hh[2], hh[3]);
        *(uint4*)&lo[obase] = make_uint4(ll[0], ll[1], ll[2], ll[3]);
    }
}

// =====================================================================
// Kernel 1b: correlation, SPLIT-K: grid (HC, B, 4).
// =====================================================================
#define KCH 128
__global__ __launch_bounds__(256) void corr_mfma_kernel(
    const ushort_t* __restrict__ qhi, const ushort_t* __restrict__ qlo,
    const ushort_t* __restrict__ khi, const ushort_t* __restrict__ klo,
    float* __restrict__ part)
{
    __shared__ ushort_t kbh[KCH * 72];
    __shared__ ushort_t kbl[KCH * 72];
    __shared__ float red[4][64][3];
    const int h = blockIdx.x, b = blockIdx.y, sl = blockIdx.z;
    const int tid = threadIdx.x;
    const int wv = tid >> 6, ln = tid & 63;
    const int lm = ln & 15, quad = ln >> 4, q8 = quad * 8;

    v8s qf[4][2][2];
#pragma unroll
    for (int mt = 0; mt < 4; ++mt)
#pragma unroll
        for (int kc = 0; kc < 2; ++kc) {
            const size_t qoff = ((size_t)b * 4096 + h * 64 + mt * 16 + lm) * 64 + kc * 32 + q8;
            qf[mt][kc][0] = *(const v8s*)&qhi[qoff];
            qf[mt][kc][1] = *(const v8s*)&qlo[qoff];
        }

    float P[4][4][3];
#pragma unroll
    for (int mt = 0; mt < 4; ++mt)
#pragma unroll
        for (int i = 0; i < 4; ++i)
            P[mt][i][0] = P[mt][i][1] = P[mt][i][2] = 0.f;

    const size_t kbase = (size_t)b * 4096 * 64;
    for (int c = 0; c < 1024 / KCH; ++c) {
        const int j0 = sl * 1024 + c * KCH;
        __syncthreads();
        for (int p = tid; p < 2048; p += 256) {
            const int pl = p >> 10;
            const int r = p & 1023;
            const int key = r >> 3, chk = (r & 7) * 8;
            const ushort_t* gsrc = pl ? klo : khi;
            const uint4 v = *(const uint4*)&gsrc[kbase + (size_t)(j0 + key) * 64 + chk];
            ushort_t* dst = pl ? kbl : kbh;
            *(uint4*)&dst[key * 72 + chk] = v;
        }
        __syncthreads();

#pragma unroll
        for (int nt = 0; nt < 2; ++nt) {
            const int kb = wv * 32 + nt * 16;
            const int j = j0 + kb + lm;
            const float gx = (float)((j & 63) * 2 + 1) * (1.f / 64.f) - 1.f;
            const float gy = (float)((j >> 6) * 2 + 1) * (1.f / 64.f) - 1.f;
            const v8s bh0 = *(const v8s*)&kbh[(kb + lm) * 72 + q8];
            const v8s bh1 = *(const v8s*)&kbh[(kb + lm) * 72 + 32 + q8];
            const v8s bl0 = *(const v8s*)&kbl[(kb + lm) * 72 + q8];
            const v8s bl1 = *(const v8s*)&kbl[(kb + lm) * 72 + 32 + q8];
#pragma unroll
            for (int mt = 0; mt < 4; ++mt) {
                v4f acc = (v4f)(0.f);
                acc = __builtin_amdgcn_mfma_f32_16x16x32_bf16(qf[mt][0][0], bl0, acc, 0, 0, 0);
                acc = __builtin_amdgcn_mfma_f32_16x16x32_bf16(qf[mt][0][1], bh0, acc, 0, 0, 0);
                acc = __builtin_amdgcn_mfma_f32_16x16x32_bf16(qf[mt][0][0], bh0, acc, 0, 0, 0);
                acc = __builtin_amdgcn_mfma_f32_16x16x32_bf16(qf[mt][1][0], bl1, acc, 0, 0, 0);
                acc = __builtin_amdgcn_mfma_f32_16x16x32_bf16(qf[mt][1][1], bh1, acc, 0, 0, 0);
                acc = __builtin_amdgcn_mfma_f32_16x16x32_bf16(qf[mt][1][0], bh1, acc, 0, 0, 0);
#pragma unroll
                for (int i = 0; i < 4; ++i) {
                    const float p_ = __expf(acc[i] * 0.125f);
                    P[mt][i][0] += p_;
                    P[mt][i][1] += p_ * gx;
                    P[mt][i][2] += p_ * gy;
                }
            }
        }
    }

#pragma unroll
    for (int mt = 0; mt < 4; ++mt)
#pragma unroll
        for (int i = 0; i < 4; ++i)
#pragma unroll
            for (int d = 0; d < 3; ++d) {
                float v = P[mt][i][d];
                v += __shfl_xor(v, 1);
                v += __shfl_xor(v, 2);
                v += __shfl_xor(v, 4);
                v += __shfl_xor(v, 8);
                P[mt][i][d] = v;
            }
    if (lm == 0) {
#pragma unroll
        for (int mt = 0; mt < 4; ++mt)
#pragma unroll
            for (int i = 0; i < 4; ++i) {
                const int q = mt * 16 + quad * 4 + i;
                red[wv][q][0] = P[mt][i][0];
                red[wv][q][1] = P[mt][i][1];
                red[wv][q][2] = P[mt][i][2];
            }
    }
    __syncthreads();
    if (tid < 64) {
        const int q = tid;
        float l = 0.f, ax = 0.f, ay = 0.f;
        for (int w = 0; w < 4; ++w) {
            l += red[w][q][0]; ax += red[w][q][1]; ay += red[w][q][2];
        }
        const size_t base = (((size_t)sl * B_ + b) * 4096 + h * 64 + q) * 4;
        part[base] = l; part[base + 1] = ax; part[base + 2] = ay;
    }
}

// =====================================================================
// Kernel 1c: merge split-K partials -> cm0 (deterministic)
// =====================================================================
__global__ __launch_bounds__(256) void corr_reduce_kernel(
    const float* __restrict__ part, float* __restrict__ cm0)
{
    const int idx = blockIdx.x * 256 + threadIdx.x;   // B*JC
    const int b = idx >> 12, hq = idx & 4095;
    float l = 0.f, ax = 0.f, ay = 0.f;
    for (int s = 0; s < 4; ++s) {
        const size_t base = (((size_t)s * B_ + b) * 4096 + hq) * 4;
        l += part[base]; ax += part[base + 1]; ay += part[base + 2];
    }
    const float inv = 1.f / l;
    const size_t o = (size_t)b * 3 * JC + hq;
    cm0[o]          = ax * inv;
    cm0[o + JC]     = ay * inv;
    cm0[o + 2 * JC] = 0.f;
}

// =====================================================================
// Kernel 2: coarse concat -> SPLIT hi/lo bf16 NHWC planes [b][px][160]
// =====================================================================
__global__ __launch_bounds__(256) void coarse_concat_split(
    const void* __restrict__ f0c, const void* __restrict__ f1c,
    const float* __restrict__ cm0, ushort_t* __restrict__ hiP,
    ushort_t* __restrict__ loP, const int* __restrict__ dflag)
{
    const int f32 = *dflag;
    const int idx = blockIdx.x * 256 + threadIdx.x;   // B*JC
    const int b = idx >> 12, hw = idx & (JC - 1);
    const size_t ib = (size_t)b * CC * JC;
    ushort_t* oh = hiP + (size_t)idx * 160;
    ushort_t* ol = loP + (size_t)idx * 160;

#pragma unroll 4
    for (int c = 0; c < CC; ++c) {
        const float v = ldin(f0c, ib + (size_t)c * JC + hw, f32);
        const ushort_t h = f2bfbits(v);
        oh[c] = h; ol[c] = f2bfbits(v - bfbits2f(h));
    }

    const float gx = cm0[((size_t)b * 3 + 0) * JC + hw];
    const float gy = cm0[((size_t)b * 3 + 1) * JC + hw];
    const float x = (gx + 1.f) * 32.f - 0.5f;
    const float y = (gy + 1.f) * 32.f - 0.5f;
    const float x0f = floorf(x), y0f = floorf(y);
    const float wx = x - x0f, wy = y - y0f;
    const int x0 = (int)x0f, y0 = (int)y0f;
    const int x1 = x0 + 1, y1 = y0 + 1;
    const float vx0 = (x0 >= 0 && x0 < WC) ? 1.f : 0.f;
    const float vx1 = (x1 >= 0 && x1 < WC) ? 1.f : 0.f;
    const float vy0 = (y0 >= 0 && y0 < HC) ? 1.f : 0.f;
    const float vy1 = (y1 >= 0 && y1 < HC) ? 1.f : 0.f;
    const int cx0 = min(max(x0, 0), WC - 1), cx1 = min(max(x1, 0), WC - 1);
    const int cy0 = min(max(y0, 0), HC - 1), cy1 = min(max(y1, 0), HC - 1);
    const float w00 = (1.f - wx) * (1.f - wy) * vx0 * vy0;
    const float w01 = wx * (1.f - wy) * vx1 * vy0;
    const float w10 = (1.f - wx) * wy * vx0 * vy1;
    const float w11 = wx * wy * vx1 * vy1;
    const int i00 = cy0 * WC + cx0, i01 = cy0 * WC + cx1;
    const int i10 = cy1 * WC + cx0, i11 = cy1 * WC + cx1;

#pragma unroll 4
    for (int c = 0; c < CC; ++c) {
        const size_t pb = ib + (size_t)c * JC;
        const float v = w00 * ldin(f1c, pb + i00, f32) + w01 * ldin(f1c, pb + i01, f32)
                      + w10 * ldin(f1c, pb + i10, f32) + w11 * ldin(f1c, pb + i11, f32);
        const ushort_t h = f2bfbits(v);
        oh[64 + c] = h; ol[64 + c] = f2bfbits(v - bfbits2f(h));
    }
    {
        const ushort_t h = f2bfbits(gx);
        oh[128] = h; ol[128] = f2bfbits(gx - bfbits2f(h));
    }
    {
        const ushort_t h = f2bfbits(gy);
        oh[129] = h; ol[129] = f2bfbits(gy - bfbits2f(h));
    }
    for (int c = 130; c < 160; ++c) { oh[c] = 0; ol[c] = 0; }
}

// =====================================================================
// BN+ReLU+split elementwise: fp32 NHWC 256 -> hi/lo bf16 planes
// =====================================================================
__global__ __launch_bounds__(256) void bnrelu_split_kernel(
    const float* __restrict__ x, const float2* __restrict__ st,
    ushort_t* __restrict__ hiP, ushort_t* __restrict__ loP)
{
    const int idx = blockIdx.x * 256 + threadIdx.x;   // B*JC*32
    const int px = idx >> 5;
    const int c8 = (idx & 31) << 3;
    const float4 v0 = *(const float4*)&x[(size_t)px * 256 + c8];
    const float4 v1 = *(const float4*)&x[(size_t)px * 256 + c8 + 4];
    const float vv[8] = {v0.x, v0.y, v0.z, v0.w, v1.x, v1.y, v1.z, v1.w};
    ushort_t hh[8], ll[8];
#pragma unroll
    for (int e = 0; e < 8; ++e) {
        const float2 s = st[c8 + e];
        const float f = fmaxf((vv[e] - s.x) * s.y, 0.f);
        const ushort_t h = f2bfbits(f);
        hh[e] = h; ll[e] = f2bfbits(f - bfbits2f(h));
    }
    uint4 oh, ol;
    oh.x = (unsigned)hh[0] | ((unsigned)hh[1] << 16);
    oh.y = (unsigned)hh[2] | ((unsigned)hh[3] << 16);
    oh.z = (unsigned)hh[4] | ((unsigned)hh[5] << 16);
    oh.w = (unsigned)hh[6] | ((unsigned)hh[7] << 16);
    ol.x = (unsigned)ll[0] | ((unsigned)ll[1] << 16);
    ol.y = (unsigned)ll[2] | ((unsigned)ll[3] << 16);
    ol.z = (unsigned)ll[4] | ((unsigned)ll[5] << 16);
    ol.w = (unsigned)ll[6] | ((unsigned)ll[7] << 16);
    *(uint4*)&hiP[(size_t)px * 256 + c8] = oh;
    *(uint4*)&loP[(size_t)px * 256 + c8] = ol;
}

// =====================================================================
// Kernel 3a: COARSE 3x3 conv, split-bf16 MFMA + fused BN-stat atomics.
// R13: register double-buffered weight-fragment PREFETCH (FA/FB sets).
// Per chunk: load FA(dx0), FB(dx1); compute(FA) covers FB latency;
// load FA(dx2) covered by compute(FB); compute(FA). 8x16 px tile.
// =====================================================================
struct WFrags { v8s bh0[3], bl0[3], bh1[3], bl1[3]; };

__global__ __launch_bounds__(256, 3) void conv3x3_wsplit(
    const ushort_t* __restrict__ hiP, const ushort_t* __restrict__ loP,
    const ushort_t* __restrict__ wfrag,
    float* __restrict__ out, float* __restrict__ chsum,
    int CIP, int CO, int H, int W, int tilesX)
{
    __shared__ ushort_t actH[10 * 18 * 36];   // 12960 B
    __shared__ ushort_t actL[10 * 18 * 36];   // 12960 B
    __shared__ float smS[4][2][16], smQ[4][2][16];   // 1 KB

    const int nch = CIP >> 5;
    const int tid = threadIdx.x;
    const int tile = blockIdx.x;
    const int b = blockIdx.y;
    const int cog = blockIdx.z;
    const int ty = (tile / tilesX) * 8;
    const int tx = (tile % tilesX) * 16;
    const int wv = tid >> 6;
    const int ln = tid & 63;
    const int lm = ln & 15;
    const int q8 = (ln >> 4) * 8;
    const size_t step = (size_t)nch * 64;

    v4f acc[2][2];
#pragma unroll
    for (int i = 0; i < 2; ++i)
#pragma unroll
        for (int j = 0; j < 2; ++j) acc[i][j] = (v4f)(0.f);

    WFrags FA, FB;

    auto loadF = [&](WFrags& F, int ch, int dx) {
#pragma unroll
        for (int dy = 0; dy < 3; ++dy) {
            const int k = dy * 3 + dx;
            const size_t fb = (((size_t)(cog * 9 + k) * 4) * nch + ch) * 64 + ln;
            F.bh0[dy] = *(const v8s*)&wfrag[fb * 8];
            F.bl0[dy] = *(const v8s*)&wfrag[(fb + step) * 8];
            F.bh1[dy] = *(const v8s*)&wfrag[(fb + 2 * step) * 8];
            F.bl1[dy] = *(const v8s*)&wfrag[(fb + 3 * step) * 8];
        }
    };
    auto computeF = [&](const WFrags& F, int dx) {
#pragma unroll
        for (int dy = 0; dy < 3; ++dy) {
#pragma unroll
            for (int mt = 0; mt < 2; ++mt) {
                const int aoff = ((wv * 2 + mt + dy) * 18 + lm + dx) * 36 + q8;
                const v8s a_h = *(const v8s*)&actH[aoff];
                const v8s a_l = *(const v8s*)&actL[aoff];
                acc[mt][0] = __builtin_amdgcn_mfma_f32_16x16x32_bf16(a_h, F.bl0[dy], acc[mt][0], 0, 0, 0);
                acc[mt][0] = __builtin_amdgcn_mfma_f32_16x16x32_bf16(a_l, F.bh0[dy], acc[mt][0], 0, 0, 0);
                acc[mt][0] = __builtin_amdgcn_mfma_f32_16x16x32_bf16(a_h, F.bh0[dy], acc[mt][0], 0, 0, 0);
                acc[mt][1] = __builtin_amdgcn_mfma_f32_16x16x32_bf16(a_h, F.bl1[dy], acc[mt][1], 0, 0, 0);
                acc[mt][1] = __builtin_amdgcn_mfma_f32_16x16x32_bf16(a_l, F.bh1[dy], acc[mt][1], 0, 0, 0);
                acc[mt][1] = __builtin_amdgcn_mfma_f32_16x16x32_bf16(a_h, F.bh1[dy], acc[mt][1], 0, 0, 0);
            }
        }
    };

    for (int ch = 0; ch < nch; ++ch) {
        const int ci0 = ch << 5;
        __syncthreads();
        // stage: 2 planes x 10x18 px x 32 ci (1440 uint4)
        for (int p = tid; p < 1440; p += 256) {
            const int pl = (p >= 720) ? 1 : 0;
            const int r = p - pl * 720;
            const int yy = r / 72;
            const int rem = r - yy * 72;
            const int xx = rem >> 2;
            const int cs = (rem & 3) << 3;
            const int gy = ty + yy - 1, gx = tx + xx - 1;
            uint4 val = make_uint4(0u, 0u, 0u, 0u);
            if (gy >= 0 && gy < H && gx >= 0 && gx < W) {
                const ushort_t* src = pl ? loP : hiP;
                val = *(const uint4*)&src[(((size_t)(b * H + gy)) * W + gx) * CIP + ci0 + cs];
            }
            ushort_t* dst = pl ? actL : actH;
            *(uint4*)&dst[(yy * 18 + xx) * 36 + cs] = val;
        }
        __syncthreads();

        loadF(FA, ch, 0);
        loadF(FB, ch, 1);
        computeF(FA, 0);     // covers FB's load latency
        loadF(FA, ch, 2);
        computeF(FB, 1);     // covers FA(dx2)'s load latency
        computeF(FA, 2);
    }

    // D layout: col(n=co)=ln&15, row(m=x)=(ln>>4)*4+i
#pragma unroll
    for (int mt = 0; mt < 2; ++mt) {
        const int y = ty + wv * 2 + mt;
#pragma unroll
        for (int nt = 0; nt < 2; ++nt) {
            const int co = cog * 32 + nt * 16 + lm;
#pragma unroll
            for (int i = 0; i < 4; ++i) {
                const int x = tx + ((ln >> 4) << 2) + i;
                out[(((size_t)(b * H + y)) * W + x) * CO + co] = acc[mt][nt][i];
            }
        }
    }

    // ---- fused BN-stat partial sums (per-channel sum & sumsq) ----
    float s0 = 0.f, s1 = 0.f, q0 = 0.f, q1 = 0.f;
#pragma unroll
    for (int mt = 0; mt < 2; ++mt)
#pragma unroll
        for (int i = 0; i < 4; ++i) {
            float v = acc[mt][0][i]; s0 += v; q0 += v * v;
            v = acc[mt][1][i]; s1 += v; q1 += v * v;
        }
    s0 += __shfl_xor(s0, 16); s0 += __shfl_xor(s0, 32);
    s1 += __shfl_xor(s1, 16); s1 += __shfl_xor(s1, 32);
    q0 += __shfl_xor(q0, 16); q0 += __shfl_xor(q0, 32);
    q1 += __shfl_xor(q1, 16); q1 += __shfl_xor(q1, 32);
    __syncthreads();
    if (ln < 16) {
        smS[wv][0][ln] = s0; smS[wv][1][ln] = s1;
        smQ[wv][0][ln] = q0; smQ[wv][1][ln] = q1;
    }
    __syncthreads();
    if (tid < 32) {
        const int nt = tid >> 4, l2 = tid & 15;
        float S = 0.f, Q = 0.f;
        for (int w = 0; w < 4; ++w) { S += smS[w][nt][l2]; Q += smQ[w][nt][l2]; }
        const int co = cog * 32 + nt * 16 + l2;
        atomicAdd(&chsum[2 * co], S);
        atomicAdd(&chsum[2 * co + 1], Q);
    }
}

// =====================================================================
// Kernel 3b: FINE 3x3 conv, single-bf16 MFMA + fused BN-stat atomics.
// R13: reverted to R11's 16x16 tile (R12's 8x16 doubled weight-staging
// traffic and cost +47 us on fine layers).
// =====================================================================
template <bool BN>
__global__ __launch_bounds__(256) void conv3x3_mfma(
    const ushort_t* __restrict__ in,
    const ushort_t* __restrict__ wp,   // [9][CO][CI] bf16
    const float2* __restrict__ stats,
    ushort_t* __restrict__ out, float* __restrict__ chsum,
    int CI, int CO, int H, int W, int tilesX)
{
    __shared__ ushort_t act[18 * 18 * 40];
    __shared__ ushort_t wbuf[9 * 32 * 40];
    __shared__ float2 st[256];
    __shared__ float smS[4][2][16], smQ[4][2][16];

    const int tid = threadIdx.x;
    const int tile = blockIdx.x;
    const int b = blockIdx.y;
    const int cog = blockIdx.z;
    const int ty = (tile / tilesX) * 16;
    const int tx = (tile % tilesX) * 16;
    const int wv = tid >> 6;
    const int ln = tid & 63;
    const int lm = ln & 15;
    const int q8 = (ln >> 4) * 8;

    if (BN) for (int c = tid; c < CI; c += 256) st[c] = stats[c];

    v4f acc[4][2];
#pragma unroll
    for (int i = 0; i < 4; ++i)
#pragma unroll
        for (int j = 0; j < 2; ++j) acc[i][j] = (v4f)(0.f);

    const int nChunks = CI >> 5;
    for (int ch = 0; ch < nChunks; ++ch) {
        const int ci0 = ch << 5;
        __syncthreads();
        for (int p = tid; p < 1296; p += 256) {
            const int yy = p / 72;
            const int rem = p - yy * 72;
            const int xx = rem >> 2;
            const int cs = (rem & 3) << 3;
            const int gy = ty + yy - 1, gx = tx + xx - 1;
            uint4 val = make_uint4(0u, 0u, 0u, 0u);
            if (gy >= 0 && gy < H && gx >= 0 && gx < W) {
                const ushort_t* gp = in + (((size_t)(b * H + gy)) * W + gx) * CI + ci0 + cs;
                val = *(const uint4*)gp;
                if (BN) {
                    unsigned u[4] = {val.x, val.y, val.z, val.w};
                    unsigned o[4];
#pragma unroll
                    for (int e = 0; e < 4; ++e) {
                        float lo = bfbits2f(u[e] & 0xffffu);
                        float hi = bfbits2f(u[e] >> 16);
                        const float2 s0 = st[ci0 + cs + 2 * e];
                        const float2 s1 = st[ci0 + cs + 2 * e + 1];
                        lo = fmaxf((lo - s0.x) * s0.y, 0.f);
                        hi = fmaxf((hi - s1.x) * s1.y, 0.f);
                        o[e] = (unsigned)f2bfbits(lo) | ((unsigned)f2bfbits(hi) << 16);
                    }
                    val = make_uint4(o[0], o[1], o[2], o[3]);
                }
            }
            *(uint4*)&act[(yy * 18 + xx) * 40 + cs] = val;
        }
        for (int p = tid; p < 1152; p += 256) {
            const int k = p / 128;
            const int rem = p - k * 128;
            const int co = rem >> 2;
            const int cs = (rem & 3) << 3;
            const ushort_t* gp = wp + ((size_t)k * CO + cog * 32 + co) * CI + ci0 + cs;
            *(uint4*)&wbuf[(k * 32 + co) * 40 + cs] = *(const uint4*)gp;
        }
        __syncthreads();

#pragma unroll
        for (int dx = 0; dx < 3; ++dx) {
            v8s af[6];
#pragma unroll
            for (int rr = 0; rr < 6; ++rr)
                af[rr] = *(const v8s*)&act[((wv * 4 + rr) * 18 + lm + dx) * 40 + q8];
#pragma unroll
            for (int dy = 0; dy < 3; ++dy) {
                const int k = dy * 3 + dx;
                const v8s bf0 = *(const v8s*)&wbuf[(k * 32 + lm) * 40 + q8];
                const v8s bf1 = *(const v8s*)&wbuf[(k * 32 + 16 + lm) * 40 + q8];
#pragma unroll
                for (int mt = 0; mt < 4; ++mt) {
                    acc[mt][0] = __builtin_amdgcn_mfma_f32_16x16x32_bf16(af[mt + dy], bf0, acc[mt][0], 0, 0, 0);
                    acc[mt][1] = __builtin_amdgcn_mfma_f32_16x16x32_bf16(af[mt + dy], bf1, acc[mt][1], 0, 0, 0);
                }
            }
        }
    }

#pragma unroll
    for (int mt = 0; mt < 4; ++mt) {
        const int y = ty + wv * 4 + mt;
#pragma unroll
        for (int nt = 0; nt < 2; ++nt) {
            const int co = cog * 32 + nt * 16 + lm;
#pragma unroll
            for (int i = 0; i < 4; ++i) {
                const int x = tx + ((ln >> 4) << 2) + i;
                out[(((size_t)(b * H + y)) * W + x) * CO + co] = f2bfbits(acc[mt][nt][i]);
            }
        }
    }

    // ---- fused BN-stat partial sums ----
    float s0 = 0.f, s1 = 0.f, q0 = 0.f, q1 = 0.f;
#pragma unroll
    for (int mt = 0; mt < 4; ++mt)
#pragma unroll
        for (int i = 0; i < 4; ++i) {
            float v = acc[mt][0][i]; s0 += v; q0 += v * v;
            v = acc[mt][1][i]; s1 += v; q1 += v * v;
        }
    s0 += __shfl_xor(s0, 16); s0 += __shfl_xor(s0, 32);
    s1 += __shfl_xor(s1, 16); s1 += __shfl_xor(s1, 32);
    q0 += __shfl_xor(q0, 16); q0 += __shfl_xor(q0, 32);
    q1 += __shfl_xor(q1, 16); q1 += __shfl_xor(q1, 32);
    __syncthreads();
    if (ln < 16) {
        smS[wv][0][ln] = s0; smS[wv][1][ln] = s1;
        smQ[wv][0][ln] = q0; smQ[wv][1][ln] = q1;
    }
    __syncthreads();
    if (tid < 32) {
        const int nt = tid >> 4, l2 = tid & 15;
        float S = 0.f, Q = 0.f;
        for (int w = 0; w < 4; ++w) { S += smS[w][nt][l2]; Q += smQ[w][nt][l2]; }
        const int co = cog * 32 + nt * 16 + l2;
        atomicAdd(&chsum[2 * co], S);
        atomicAdd(&chsum[2 * co + 1], Q);
    }
}

// =====================================================================
// stats finalize: (sum, sumsq) -> (mean, rsqrt(var+eps))
// =====================================================================
__global__ void stats_finalize_kernel(const float* __restrict__ chsum,
                                      float2* __restrict__ st, int C, float inv_n)
{
    const int c = threadIdx.x;
    if (c >= C) return;
    const float mean = chsum[2 * c] * inv_n;
    const float var = chsum[2 * c + 1] * inv_n - mean * mean;
    st[c] = make_float2(mean, 1.0f / sqrtf(var + 1e-5f));
}

// =====================================================================
// Kernel 5: coarse head (fp32 NHWC): 1x1 conv 256->3 + bias + cm0
// =====================================================================
__global__ __launch_bounds__(256) void coarse_head_kernel(
    const float* __restrict__ A, const float2* __restrict__ stats,
    const void* __restrict__ w5, const void* __restrict__ b5,
    float* __restrict__ cm0, void* __restrict__ out,
    const int* __restrict__ dflag)
{
    const int f32 = *dflag;
    __shared__ float wl[3][256];
    __shared__ float bl[3];
    __shared__ float2 st[256];
    const int tid = threadIdx.x;
    for (int i = tid; i < 768; i += 256) wl[i >> 8][i & 255] = ldin(w5, i, f32);
    if (tid < 3) bl[tid] = ldin(b5, tid, f32);
    st[tid] = stats[tid];
    __syncthreads();

    const int idx = blockIdx.x * 256 + tid;
    const int b = idx >> 12, hw = idx & (JC - 1);
    float a0 = bl[0], a1 = bl[1], a2 = bl[2];
    const float* p = A + (size_t)idx * 256;
    for (int c = 0; c < 256; c += 4) {
        const float4 raw = *(const float4*)(p + c);
        const float rv[4] = {raw.x, raw.y, raw.z, raw.w};
#pragma unroll
        for (int e = 0; e < 4; ++e) {
            const int cc = c + e;
            const float v = fmaxf((rv[e] - st[cc].x) * st[cc].y, 0.f);
            a0 += v * wl[0][cc]; a1 += v * wl[1][cc]; a2 += v * wl[2][cc];
        }
    }
    const size_t base = (size_t)b * 3 * JC + hw;
    const float c0 = cm0[base] + a0;
    const float c1 = cm0[base + JC] + a1;
    const float c2 = cm0[base + 2 * JC] + a2;
    cm0[base] = c0; cm0[base + JC] = c1; cm0[base + 2 * JC] = c2;
    stout(out, base, c0, f32);
    stout(out, base + JC, c1, f32);
    stout(out, base + 2 * JC, c2, f32);
}

// =====================================================================
// Kernel 6: bilinear 2x upsample (half-pixel, edge clamp)
// =====================================================================
__global__ __launch_bounds__(256) void upsample_kernel(
    const float* __restrict__ cm, float* __restrict__ up)
{
    const int idx = blockIdx.x * 256 + threadIdx.x;
    const int ox = idx & 127, oy = (idx >> 7) & 127, bc = idx >> 14;
    const float sx = ox * 0.5f - 0.25f;
    const float sy = oy * 0.5f - 0.25f;
    const int x0 = (int)floorf(sx), y0 = (int)floorf(sy);
    const float fx = sx - x0, fy = sy - y0;
    const int cx0 = max(x0, 0), cx1 = min(x0 + 1, WC - 1);
    const int cy0 = max(y0, 0), cy1 = min(y0 + 1, HC - 1);
    const float* p = cm + (size_t)bc * JC;
    const float v = (1.f - fy) * ((1.f - fx) * p[cy0 * WC + cx0] + fx * p[cy0 * WC + cx1])
                  + fy * ((1.f - fx) * p[cy1 * WC + cx0] + fx * p[cy1 * WC + cx1]);
    up[idx] = v;
}

// =====================================================================
// Kernel 7: fine concat -> NHWC bf16 [b][y][x][64] (50 real + 14 zero)
// =====================================================================
__global__ __launch_bounds__(256) void fine_concat_nhwc(
    const void* __restrict__ f0f, const void* __restrict__ f1f,
    const float* __restrict__ up, ushort_t* __restrict__ A,
    const int* __restrict__ dflag)
{
    const int f32 = *dflag;
    const int idx = blockIdx.x * 256 + threadIdx.x;   // B*JF
    const int b = idx >> 14, hw = idx & (JF - 1);
    const size_t ib = (size_t)b * CF * JF;
    ushort_t* o = A + (size_t)idx * 64;

    for (int c = 0; c < CF; ++c)
        o[c] = f2bfbits(ldin(f0f, ib + (size_t)c * JF + hw, f32));

    const size_t ub = (size_t)b * 3 * JF + hw;
    const float gx = up[ub], gy = up[ub + JF];
    const float x = (gx + 1.f) * 64.f - 0.5f;
    const float y = (gy + 1.f) * 64.f - 0.5f;
    const float x0f = floorf(x), y0f = floorf(y);
    const float wx = x - x0f, wy = y - y0f;
    const int x0 = (int)x0f, y0 = (int)y0f;
    const int x1 = x0 + 1, y1 = y0 + 1;
    const float vx0 = (x0 >= 0 && x0 < WF) ? 1.f : 0.f;
    const float vx1 = (x1 >= 0 && x1 < WF) ? 1.f : 0.f;
    const float vy0 = (y0 >= 0 && y0 < HF) ? 1.f : 0.f;
    const float vy1 = (y1 >= 0 && y1 < HF) ? 1.f : 0.f;
    const int cx0 = min(max(x0, 0), WF - 1), cx1 = min(max(x1, 0), WF - 1);
    const int cy0 = min(max(y0, 0), HF - 1), cy1 = min(max(y1, 0), HF - 1);
    const float w00 = (1.f - wx) * (1.f - wy) * vx0 * vy0;
    const float w01 = wx * (1.f - wy) * vx1 * vy0;
    const float w10 = (1.f - wx) * wy * vx0 * vy1;
    const float w11 = wx * wy * vx1 * vy1;
    const int i00 = cy0 * WF + cx0, i01 = cy0 * WF + cx1;
    const int i10 = cy1 * WF + cx0, i11 = cy1 * WF + cx1;

    for (int c = 0; c < CF; ++c) {
        const size_t pb = ib + (size_t)c * JF;
        const float v = w00 * ldin(f1f, pb + i00, f32) + w01 * ldin(f1f, pb + i01, f32)
                      + w10 * ldin(f1f, pb + i10, f32) + w11 * ldin(f1f, pb + i11, f32);
        o[24 + c] = f2bfbits(v);
    }
    o[48] = f2bfbits(gx);
    o[49] = f2bfbits(gy);
    for (int c = 50; c < 64; ++c) o[c] = 0;
}

// =====================================================================
// Kernel 8: fine head (NHWC bf16): 1x1 conv 64->3 + bias + up -> out1
// =====================================================================
__global__ __launch_bounds__(256) void fine_head_kernel(
    const ushort_t* __restrict__ A, const float2* __restrict__ stats,
    const void* __restrict__ w5, const void* __restrict__ b5,
    const float* __restrict__ up, void* __restrict__ out,
    const int* __restrict__ dflag)
{
    const int f32 = *dflag;
    __shared__ float wl[3][64];
    __shared__ float bl[3];
    __shared__ float2 st[64];
    const int tid = threadIdx.x;
    if (tid < 192) wl[tid >> 6][tid & 63] = ldin(w5, tid, f32);
    if (tid < 3) bl[tid] = ldin(b5, tid, f32);
    if (tid < 64) st[tid] = stats[tid];
    __syncthreads();

    const int idx = blockIdx.x * 256 + tid;
    const int b = idx >> 14, hw = idx & (JF - 1);
    float a0 = bl[0], a1 = bl[1], a2 = bl[2];
    const ushort_t* p = A + (size_t)idx * 64;
    for (int c = 0; c < 64; c += 8) {
        const uint4 raw = *(const uint4*)(p + c);
        const unsigned u[4] = {raw.x, raw.y, raw.z, raw.w};
#pragma unroll
        for (int e = 0; e < 4; ++e) {
            const int c0 = c + 2 * e, c1 = c0 + 1;
            float lo = bfbits2f(u[e] & 0xffffu);
            float hi = bfbits2f(u[e] >> 16);
            lo = fmaxf((lo - st[c0].x) * st[c0].y, 0.f);
            hi = fmaxf((hi - st[c1].x) * st[c1].y, 0.f);
            a0 += lo * wl[0][c0] + hi * wl[0][c1];
            a1 += lo * wl[1][c0] + hi * wl[1][c1];
            a2 += lo * wl[2][c0] + hi * wl[2][c1];
        }
    }
    const size_t base = (size_t)b * 3 * JF + hw;
    stout(out, OUT0_ELEMS + base,          up[base] + a0, f32);
    stout(out, OUT0_ELEMS + base + JF,     up[base + JF] + a1, f32);
    stout(out, OUT0_ELEMS + base + 2 * JF, up[base + 2 * JF] + a2, f32);
}

// =====================================================================
extern "C" void kernel_launch(void* const* d_in, const int* in_sizes, int n_in,
                              void* d_out, int out_size, void* d_ws, size_t ws_size,
                              hipStream_t stream)
{
    const void* f0c = d_in[0];
    const void* f1c = d_in[1];
    const void* f0f = d_in[2];
    const void* f1f = d_in[3];
    const void* cw1 = d_in[4];
    const void* cw2 = d_in[5];
    const void* cw3 = d_in[6];
    const void* cw4 = d_in[7];
    const void* cw5 = d_in[8];
    const void* cb5 = d_in[9];
    const void* fw1 = d_in[10];
    const void* fw2 = d_in[11];
    const void* fw3 = d_in[12];
    const void* fw4 = d_in[13];
    const void* fw5 = d_in[14];
    const void* fb5 = d_in[15];

    // ---- workspace layout (same proven footprint) ----
    char* wsb = (char*)d_ws;
    float* bufA    = (float*)wsb;                       // 16 MiB
    float* bufB    = (float*)(wsb + 16777216);          // 16 MiB
    float* cm0     = (float*)(wsb + 33554432);          // 196,608 B
    float* up      = (float*)(wsb + 33751040);          // 786,432 B
    float* chsum   = (float*)(wsb + 34537472);          // 2,048 B
    float2* st_g   = (float2*)(wsb + 34668544);         // 2,048 B
    int* dflag     = (int*)(wsb + 34670592);            // 64 B
    ushort_t* fwp  = (ushort_t*)(wsb + 34670656);       // 294,912 B
    ushort_t* fw1p = fwp;
    ushort_t* fw2p = fwp + 36864;
    ushort_t* fw3p = fwp + 73728;
    ushort_t* fw4p = fwp + 110592;
    ushort_t* wfrag = (ushort_t*)(wsb + 34965568);      // up to 9,437,184 B

    // split activation planes: hi = bufA[0..8MB), lo = bufA[8..16MB)
    ushort_t* hiP = (ushort_t*)bufA;
    ushort_t* loP = (ushort_t*)(wsb + 8388608);

    // corr split Q/K planes in bufA's first 8 MB (dead before concat)
    ushort_t* qhi = (ushort_t*)bufA;
    ushort_t* qlo = qhi + 1048576;
    ushort_t* khi = qlo + 1048576;
    ushort_t* klo = khi + 1048576;
    float* cpart = (float*)bufB;   // 1 MB corr partials (bufB dead during corr)

    ushort_t* fF1 = (ushort_t*)bufB;   // fine ping
    ushort_t* fF2 = (ushort_t*)bufA;   // fine pong

    // 0. dtype probe
    dtype_probe_kernel<<<1, 256, 0, stream>>>((const ushort_t*)f0c, dflag);

    // fine weight repacks (bf16 [k][co][ci_pad])
    repack_w_kernel<<<(9 * 64 * 64 + 255) / 256, 256, 0, stream>>>(fw1, fw1p, 64, 50, 64, dflag);
    repack_w_kernel<<<(9 * 64 * 64 + 255) / 256, 256, 0, stream>>>(fw2, fw2p, 64, 64, 64, dflag);
    repack_w_kernel<<<(9 * 64 * 64 + 255) / 256, 256, 0, stream>>>(fw3, fw3p, 64, 64, 64, dflag);
    repack_w_kernel<<<(9 * 64 * 64 + 255) / 256, 256, 0, stream>>>(fw4, fw4p, 64, 64, 64, dflag);

    // 1. correlation: split-transpose Q/K, split-K MFMA, reduce
    split_transpose_kernel<<<dim3(B_ * 64), 256, 0, stream>>>(f0c, qhi, qlo, dflag);
    split_transpose_kernel<<<dim3(B_ * 64), 256, 0, stream>>>(f1c, khi, klo, dflag);
    corr_mfma_kernel<<<dim3(HC, B_, 4), 256, 0, stream>>>(qhi, qlo, khi, klo, cpart);
    corr_reduce_kernel<<<dim3(B_ * JC / 256), 256, 0, stream>>>(cpart, cm0);

    // 2. coarse concat -> split planes (CIP=160); overwrites q/k (dead)
    coarse_concat_split<<<dim3(B_ * JC / 256), 256, 0, stream>>>(f0c, f1c, cm0, hiP, loP, dflag);

    // 3. coarse conv stack: 8x16 tiles, 1024 blocks, fragment prefetch
    const dim3 cgrid(32, B_, 8);
    repack_wfrag_kernel<<<(8 * 9 * 2 * 2 * 5 * 64 + 255) / 256, 256, 0, stream>>>(cw1, wfrag, 130, 5, dflag);
    hipMemsetAsync(chsum, 0, 2048, stream);
    conv3x3_wsplit<<<cgrid, 256, 0, stream>>>(hiP, loP, wfrag, bufB, chsum, 160, 256, HC, WC, 4);
    stats_finalize_kernel<<<1, 256, 0, stream>>>(chsum, st_g, 256, 1.f / 16384.f);

    bnrelu_split_kernel<<<B_ * JC * 32 / 256, 256, 0, stream>>>(bufB, st_g, hiP, loP);
    repack_wfrag_kernel<<<(8 * 9 * 2 * 2 * 8 * 64 + 255) / 256, 256, 0, stream>>>(cw2, wfrag, 256, 8, dflag);
    hipMemsetAsync(chsum, 0, 2048, stream);
    conv3x3_wsplit<<<cgrid, 256, 0, stream>>>(hiP, loP, wfrag, bufB, chsum, 256, 256, HC, WC, 4);
    stats_finalize_kernel<<<1, 256, 0, stream>>>(chsum, st_g, 256, 1.f / 16384.f);

    bnrelu_split_kernel<<<B_ * JC * 32 / 256, 256, 0, stream>>>(bufB, st_g, hiP, loP);
    repack_wfrag_kernel<<<(8 * 9 * 2 * 2 * 8 * 64 + 255) / 256, 256, 0, stream>>>(cw3, wfrag, 256, 8, dflag);
    hipMemsetAsync(chsum, 0, 2048, stream);
    conv3x3_wsplit<<<cgrid, 256, 0, stream>>>(hiP, loP, wfrag, bufB, chsum, 256, 256, HC, WC, 4);
    stats_finalize_kernel<<<1, 256, 0, stream>>>(chsum, st_g, 256, 1.f / 16384.f);

    bnrelu_split_kernel<<<B_ * JC * 32 / 256, 256, 0, stream>>>(bufB, st_g, hiP, loP);
    repack_wfrag_kernel<<<(8 * 9 * 2 * 2 * 8 * 64 + 255) / 256, 256, 0, stream>>>(cw4, wfrag, 256, 8, dflag);
    hipMemsetAsync(chsum, 0, 2048, stream);
    conv3x3_wsplit<<<cgrid, 256, 0, stream>>>(hiP, loP, wfrag, bufB, chsum, 256, 256, HC, WC, 4);
    stats_finalize_kernel<<<1, 256, 0, stream>>>(chsum, st_g, 256, 1.f / 16384.f);

    // 4. coarse head -> out0, cmatch (in place over cm0)
    coarse_head_kernel<<<dim3(B_ * JC / 256), 256, 0, stream>>>(bufB, st_g, cw5, cb5, cm0, d_out, dflag);

    // 5. upsample (cm0 now holds cmatch)
    upsample_kernel<<<dim3(B_ * 3 * JF / 256), 256, 0, stream>>>(cm0, up);

    // 6. fine concat -> fF1 (bufB region; conv4 raw dead after head)
    fine_concat_nhwc<<<dim3(B_ * JF / 256), 256, 0, stream>>>(f0f, f1f, up, fF1, dflag);

    // 7. fine conv stack: 16x16 tiles (R11), fused stats
    const dim3 fgrid(64, B_, 2);
    hipMemsetAsync(chsum, 0, 512, stream);
    conv3x3_mfma<false><<<fgrid, 256, 0, stream>>>(fF1, fw1p, nullptr, fF2, chsum, 64, 64, HF, WF, 8);
    stats_finalize_kernel<<<1, 256, 0, stream>>>(chsum, st_g, 64, 1.f / 65536.f);
    hipMemsetAsync(chsum, 0, 512, stream);
    conv3x3_mfma<true><<<fgrid, 256, 0, stream>>>(fF2, fw2p, st_g, fF1, chsum, 64, 64, HF, WF, 8);
    stats_finalize_kernel<<<1, 256, 0, stream>>>(chsum, st_g, 64, 1.f / 65536.f);
    hipMemsetAsync(chsum, 0, 512, stream);
    conv3x3_mfma<true><<<fgrid, 256, 0, stream>>>(fF1, fw3p, st_g, fF2, chsum, 64, 64, HF, WF, 8);
    stats_finalize_kernel<<<1, 256, 0, stream>>>(chsum, st_g, 64, 1.f / 65536.f);
    hipMemsetAsync(chsum, 0, 512, stream);
    conv3x3_mfma<true><<<fgrid, 256, 0, stream>>>(fF2, fw4p, st_g, fF1, chsum, 64, 64, HF, WF, 8);
    stats_finalize_kernel<<<1, 256, 0, stream>>>(chsum, st_g, 64, 1.f / 65536.f);

    // 8. fine head -> out1
    fine_head_kernel<<<dim3(B_ * JF / 256), 256, 0, stream>>>(fF1, st_g, fw5, fb5, up, d_out, dflag);
}